// Round 6
// baseline (261.735 us; speedup 1.0000x reference)
//
#include <hip/hip_runtime.h>

typedef unsigned short ushort_t;
typedef __attribute__((ext_vector_type(8))) short short8;
typedef __attribute__((ext_vector_type(4))) float f32x4;

#define LOG2E 1.44269504088896f

// async global->LDS, 16B per lane. LDS dest must be wave-uniform base + lane*16.
__device__ __forceinline__ void async16(const void* g, void* l) {
  __builtin_amdgcn_global_load_lds(
      (const __attribute__((address_space(1))) void*)g,
      (__attribute__((address_space(3))) void*)l, 16, 0, 0);
}

__device__ __forceinline__ ushort_t f2bf(float f) {
  union { float f; unsigned u; } x; x.f = f;
  unsigned u = x.u;
  u += 0x7fffu + ((u >> 16) & 1u);
  return (ushort_t)(u >> 16);
}

__device__ __forceinline__ float bf2f(ushort_t w) {
  union { unsigned u; float f; } x; x.u = ((unsigned)w) << 16;
  return x.f;
}

// ---------------- split ingest: fp32 -> (hi, lo) bf16 ----------------
__global__ __launch_bounds__(256) void split8(const float* __restrict__ src,
                                              ushort_t* __restrict__ hi,
                                              ushort_t* __restrict__ lo, int n8) {
  int i = blockIdx.x * 256 + threadIdx.x;
  if (i >= n8) return;
  const f32x4* s = (const f32x4*)src;
  f32x4 a = s[i * 2], b = s[i * 2 + 1];
  short8 oh, ol;
  #pragma unroll
  for (int j = 0; j < 4; j++) {
    ushort_t h = f2bf(a[j]); oh[j] = (short)h; ol[j] = (short)f2bf(a[j] - bf2f(h));
    h = f2bf(b[j]); oh[j + 4] = (short)h; ol[j + 4] = (short)f2bf(b[j] - bf2f(h));
  }
  ((short8*)hi)[i] = oh;
  ((short8*)lo)[i] = ol;
}

// ------- weight transpose+split: src fp32 [K][Nn] -> dstT hi/lo bf16 [Nn][K] -------
__global__ __launch_bounds__(256) void transpose_split(const float* __restrict__ src,
                                                       ushort_t* __restrict__ dh,
                                                       ushort_t* __restrict__ dl,
                                                       int K, int Nn) {
  __shared__ float tile[32][33];
  int bx = blockIdx.x * 32;  // Nn dim
  int by = blockIdx.y * 32;  // K dim
  int tx = threadIdx.x, ty = threadIdx.y;  // (32, 8)
  #pragma unroll
  for (int i = 0; i < 32; i += 8)
    tile[ty + i][tx] = src[(size_t)(by + ty + i) * Nn + bx + tx];
  __syncthreads();
  #pragma unroll
  for (int i = 0; i < 32; i += 8) {
    float v = tile[tx][ty + i];
    ushort_t h = f2bf(v);
    size_t idx = (size_t)(bx + ty + i) * K + by + tx;
    dh[idx] = h;
    dl[idx] = f2bf(v - bf2f(h));
  }
}

// ---- split GEMM: C = (Ah+Al)[M][K] @ (Bh+Bl)[Nn][K]^T, 3-product bf16x3 ----
// 128x128 tile, BK=32, 4 waves (2x2), each wave 64x64 as 4x4 of 16x16x32 MFMA.
// EPI 0: C -> (o_hi,o_lo) q-layout [B*H][N][D]
// EPI 1: col<512 -> (o_hi,o_lo) k-layout [B*H][N][D]; col>=512 -> o_vt bf16 [B*H][D][N]
// EPI 2: outf fp32 row-major [M][ldo]  (final output)
template<int EPI>
__global__ __launch_bounds__(256) void gemm3_bt(const ushort_t* __restrict__ Ah,
                                                const ushort_t* __restrict__ Al,
                                                const ushort_t* __restrict__ Bh,
                                                const ushort_t* __restrict__ Bl,
                                                ushort_t* __restrict__ o_hi,
                                                ushort_t* __restrict__ o_lo,
                                                ushort_t* __restrict__ o_vt,
                                                float* __restrict__ outf,
                                                int K, int ldo) {
  __shared__ __align__(16) ushort_t Ash[128 * 32];
  __shared__ __align__(16) ushort_t Asl[128 * 32];
  __shared__ __align__(16) ushort_t Bsh[128 * 32];
  __shared__ __align__(16) ushort_t Bsl[128 * 32];
  const int tid = threadIdx.x;
  const int wave = tid >> 6, lane = tid & 63;
  const int wm = (wave >> 1) * 64, wn = (wave & 1) * 64;
  const int m0 = blockIdx.y * 128, n0 = blockIdx.x * 128;
  const int lrow = lane & 15, lq = lane >> 4;

  f32x4 acc[4][4];
  const f32x4 z = {0.f, 0.f, 0.f, 0.f};
  #pragma unroll
  for (int i = 0; i < 4; i++)
    #pragma unroll
    for (int j = 0; j < 4; j++) acc[i][j] = z;

  for (int k0 = 0; k0 < K; k0 += 32) {
    __syncthreads();
    #pragma unroll
    for (int i = 0; i < 2; i++) {
      int g = i * 256 + tid;        // 0..511
      int r = g >> 2, kc = g & 3;   // row, 8-elem chunk
      size_t ga = (size_t)(m0 + r) * K + k0 + kc * 8;
      size_t gb = (size_t)(n0 + r) * K + k0 + kc * 8;
      async16(&Ah[ga], &Ash[g * 8]);
      async16(&Al[ga], &Asl[g * 8]);
      async16(&Bh[gb], &Bsh[g * 8]);
      async16(&Bl[gb], &Bsl[g * 8]);
    }
    __syncthreads();  // drains vmcnt(0): all 4 tiles landed

    short8 afh[4], bfr[4];
    #pragma unroll
    for (int t = 0; t < 4; t++) {
      afh[t] = *(const short8*)&Ash[(wm + t * 16 + lrow) * 32 + lq * 8];
      bfr[t] = *(const short8*)&Bsh[(wn + t * 16 + lrow) * 32 + lq * 8];
    }
    #pragma unroll
    for (int ti = 0; ti < 4; ti++)
      #pragma unroll
      for (int tj = 0; tj < 4; tj++)
        acc[ti][tj] = __builtin_amdgcn_mfma_f32_16x16x32_bf16(afh[ti], bfr[tj], acc[ti][tj], 0, 0, 0);

    {
      short8 afl[4];
      #pragma unroll
      for (int t = 0; t < 4; t++)
        afl[t] = *(const short8*)&Asl[(wm + t * 16 + lrow) * 32 + lq * 8];
      #pragma unroll
      for (int ti = 0; ti < 4; ti++)
        #pragma unroll
        for (int tj = 0; tj < 4; tj++)
          acc[ti][tj] = __builtin_amdgcn_mfma_f32_16x16x32_bf16(afl[ti], bfr[tj], acc[ti][tj], 0, 0, 0);
    }
    #pragma unroll
    for (int t = 0; t < 4; t++)
      bfr[t] = *(const short8*)&Bsl[(wn + t * 16 + lrow) * 32 + lq * 8];
    #pragma unroll
    for (int ti = 0; ti < 4; ti++)
      #pragma unroll
      for (int tj = 0; tj < 4; tj++)
        acc[ti][tj] = __builtin_amdgcn_mfma_f32_16x16x32_bf16(afh[ti], bfr[tj], acc[ti][tj], 0, 0, 0);
  }

  // epilogue: C row m = m0+wm+ti*16+lq*4+r ; col = n0+wn+tj*16+lrow
  #pragma unroll
  for (int ti = 0; ti < 4; ti++) {
    #pragma unroll
    for (int tj = 0; tj < 4; tj++) {
      int row0 = m0 + wm + ti * 16 + lq * 4;
      int col = n0 + wn + tj * 16 + lrow;
      #pragma unroll
      for (int r = 0; r < 4; r++) {
        int m = row0 + r;
        float fv = acc[ti][tj][r];
        if (EPI == 0) {
          size_t idx = (size_t)((m >> 10) * 8 + (col >> 6)) * 65536 + (m & 1023) * 64 + (col & 63);
          ushort_t h = f2bf(fv);
          o_hi[idx] = h;
          o_lo[idx] = f2bf(fv - bf2f(h));
        } else if (EPI == 1) {
          if (col < 512) {
            size_t idx = (size_t)((m >> 10) * 8 + (col >> 6)) * 65536 + (m & 1023) * 64 + (col & 63);
            ushort_t h = f2bf(fv);
            o_hi[idx] = h;
            o_lo[idx] = f2bf(fv - bf2f(h));
          } else {
            int cc = col - 512;
            o_vt[(size_t)(((m >> 10) * 8 + (cc >> 6)) * 64 + (cc & 63)) * 1024 + (m & 1023)] = f2bf(fv);
          }
        } else {
          outf[(size_t)m * ldo + col] = fv;   // fp32 final output
        }
      }
    }
  }
}

// ---------------- flash attention (split-precision QK^T) ----------------
// grid = B*H*(N/128) = 512 blocks, 256 threads. Wave w owns 32 Q rows.
// q,k as hi/lo [BH][N][D]; vT bf16 [BH][D][N]; out hi/lo [B][N][H*D].
__global__ __launch_bounds__(256) void flash_attn(const ushort_t* __restrict__ qh,
                                                  const ushort_t* __restrict__ ql,
                                                  const ushort_t* __restrict__ kh,
                                                  const ushort_t* __restrict__ kl,
                                                  const ushort_t* __restrict__ vtb,
                                                  ushort_t* __restrict__ obh,
                                                  ushort_t* __restrict__ obl) {
  __shared__ __align__(16) ushort_t Ksh[64 * 64];      // [n][d] hi
  __shared__ __align__(16) ushort_t Ksl[64 * 64];      // [n][d] lo
  __shared__ __align__(16) ushort_t VTs[64 * 64];      // [d][n]
  __shared__ __align__(16) float Sw[4][64 * 40];       // per wave: S^T [c][r], stride 40
  __shared__ __align__(16) float albuf[4][32];
  __shared__ __align__(16) float lbuf[4][32];

  const int tid = threadIdx.x;
  const int wave = tid >> 6, lane = tid & 63;
  const int bh = blockIdx.x >> 3, qt = blockIdx.x & 7;
  const int lrow = lane & 15, lq = lane >> 4;
  // P buffer aliases this wave's Sw region (wave-private; S fully consumed
  // -- via the mx reduction dependency -- before P overwrites it).
  ushort_t* Pw = (ushort_t*)&Sw[wave][0];              // [32][80] bf16

  const ushort_t* Qh = qh + (size_t)bh * 65536;
  const ushort_t* Ql = ql + (size_t)bh * 65536;
  const ushort_t* Kph = kh + (size_t)bh * 65536;
  const ushort_t* Kpl = kl + (size_t)bh * 65536;
  const ushort_t* VT = vtb + (size_t)bh * 65536;

  const int qrow0 = qt * 128 + wave * 32;

  short8 qfh[2][2], qfl[2][2];
  #pragma unroll
  for (int mt = 0; mt < 2; mt++)
    #pragma unroll
    for (int s = 0; s < 2; s++) {
      size_t idx = (size_t)(qrow0 + mt * 16 + lrow) * 64 + s * 32 + lq * 8;
      qfh[mt][s] = *(const short8*)&Qh[idx];
      qfl[mt][s] = *(const short8*)&Ql[idx];
    }

  f32x4 oacc[2][4];
  const f32x4 z = {0.f, 0.f, 0.f, 0.f};
  #pragma unroll
  for (int mt = 0; mt < 2; mt++)
    #pragma unroll
    for (int dt = 0; dt < 4; dt++) oacc[mt][dt] = z;

  float m_i = -1e30f, l_i = 0.f;
  const int r = lane >> 1, hlf = lane & 1;

  for (int kt = 0; kt < 16; kt++) {
    __syncthreads();  // all waves done with previous K/V tiles
    #pragma unroll
    for (int i = 0; i < 2; i++) {
      int g = i * 256 + tid;      // 0..511
      int rw = g >> 3, ch = g & 7;
      size_t kidx = (size_t)(kt * 64 + rw) * 64 + ch * 8;
      async16(&Kph[kidx], &Ksh[g * 8]);
      async16(&Kpl[kidx], &Ksl[g * 8]);
      async16(&VT[(size_t)rw * 1024 + kt * 64 + ch * 8], &VTs[g * 8]);
    }
    __syncthreads();  // tiles landed

    // S = Q @ K^T with bf16x3: qh*kh + ql*kh + qh*kl
    f32x4 sacc[2][4];
    #pragma unroll
    for (int mt = 0; mt < 2; mt++)
      #pragma unroll
      for (int nt = 0; nt < 4; nt++) sacc[mt][nt] = z;
    #pragma unroll
    for (int s = 0; s < 2; s++) {
      short8 bfr[4];
      #pragma unroll
      for (int nt = 0; nt < 4; nt++)
        bfr[nt] = *(const short8*)&Ksh[(nt * 16 + lrow) * 64 + s * 32 + lq * 8];
      #pragma unroll
      for (int mt = 0; mt < 2; mt++)
        #pragma unroll
        for (int nt = 0; nt < 4; nt++) {
          sacc[mt][nt] = __builtin_amdgcn_mfma_f32_16x16x32_bf16(qfh[mt][s], bfr[nt], sacc[mt][nt], 0, 0, 0);
          sacc[mt][nt] = __builtin_amdgcn_mfma_f32_16x16x32_bf16(qfl[mt][s], bfr[nt], sacc[mt][nt], 0, 0, 0);
        }
      #pragma unroll
      for (int nt = 0; nt < 4; nt++)
        bfr[nt] = *(const short8*)&Ksl[(nt * 16 + lrow) * 64 + s * 32 + lq * 8];
      #pragma unroll
      for (int mt = 0; mt < 2; mt++)
        #pragma unroll
        for (int nt = 0; nt < 4; nt++)
          sacc[mt][nt] = __builtin_amdgcn_mfma_f32_16x16x32_bf16(qfh[mt][s], bfr[nt], sacc[mt][nt], 0, 0, 0);
    }

    // store S^T to wave-private LDS (C-layout: col=lrow+16nt, rows lq*4+reg+16mt)
    #pragma unroll
    for (int mt = 0; mt < 2; mt++)
      #pragma unroll
      for (int nt = 0; nt < 4; nt++) {
        int c = nt * 16 + lrow;
        int rr = mt * 16 + lq * 4;
        *(f32x4*)&Sw[wave][c * 40 + rr] = sacc[mt][nt];
      }
    __syncthreads();

    // online softmax: lane pair (2r, 2r+1) handles row r, 32 cols each
    float vals[32];
    float mx = -1e30f;
    #pragma unroll
    for (int j = 0; j < 32; j++) {
      vals[j] = Sw[wave][(hlf * 32 + j) * 40 + r];
      mx = fmaxf(mx, vals[j]);
    }
    mx = fmaxf(mx, __shfl_xor(mx, 1));   // consumes ALL vals -> S reads complete
    float mnew = fmaxf(m_i, mx);
    float alpha = exp2f((m_i - mnew) * LOG2E);
    float sum = 0.f;
    #pragma unroll
    for (int j8 = 0; j8 < 4; j8++) {
      short8 pk;
      #pragma unroll
      for (int j = 0; j < 8; j++) {
        float p = exp2f((vals[j8 * 8 + j] - mnew) * LOG2E);
        sum += p;
        pk[j] = (short)f2bf(p);
      }
      *(short8*)&Pw[r * 80 + hlf * 32 + j8 * 8] = pk;   // overwrites Sw alias
    }
    sum += __shfl_xor(sum, 1);
    l_i = l_i * alpha + sum;
    m_i = mnew;
    albuf[wave][r] = alpha;
    __syncthreads();

    // rescale O by alpha (per C-layout row)
    f32x4 al[2];
    #pragma unroll
    for (int mt = 0; mt < 2; mt++) al[mt] = *(f32x4*)&albuf[wave][mt * 16 + lq * 4];
    #pragma unroll
    for (int mt = 0; mt < 2; mt++)
      #pragma unroll
      for (int dt = 0; dt < 4; dt++)
        #pragma unroll
        for (int e = 0; e < 4; e++) oacc[mt][dt][e] *= al[mt][e];

    // O += P @ V
    #pragma unroll
    for (int s = 0; s < 2; s++) {
      short8 pf[2], vf[4];
      #pragma unroll
      for (int mt = 0; mt < 2; mt++)
        pf[mt] = *(const short8*)&Pw[(mt * 16 + lrow) * 80 + s * 32 + lq * 8];
      #pragma unroll
      for (int dt = 0; dt < 4; dt++)
        vf[dt] = *(const short8*)&VTs[(dt * 16 + lrow) * 64 + s * 32 + lq * 8];
      #pragma unroll
      for (int mt = 0; mt < 2; mt++)
        #pragma unroll
        for (int dt = 0; dt < 4; dt++)
          oacc[mt][dt] = __builtin_amdgcn_mfma_f32_16x16x32_bf16(pf[mt], vf[dt], oacc[mt][dt], 0, 0, 0);
    }
  }

  // finalize: divide by l, split to hi/lo, write [B][N][H*D]
  lbuf[wave][r] = l_i;
  __syncthreads();
  f32x4 li[2];
  #pragma unroll
  for (int mt = 0; mt < 2; mt++) li[mt] = *(f32x4*)&lbuf[wave][mt * 16 + lq * 4];
  const int b = bh >> 3, h = bh & 7;
  #pragma unroll
  for (int mt = 0; mt < 2; mt++)
    #pragma unroll
    for (int dt = 0; dt < 4; dt++)
      #pragma unroll
      for (int e = 0; e < 4; e++) {
        int n = qt * 128 + wave * 32 + mt * 16 + lq * 4 + e;
        int d = dt * 16 + lrow;
        float f = oacc[mt][dt][e] / li[mt][e];
        size_t idx = (size_t)(b * 1024 + n) * 512 + h * 64 + d;
        ushort_t hi = f2bf(f);
        obh[idx] = hi;
        obl[idx] = f2bf(f - bf2f(hi));
      }
}

// ---------------- launcher ----------------
extern "C" void kernel_launch(void* const* d_in, const int* in_sizes, int n_in,
                              void* d_out, int out_size, void* d_ws, size_t ws_size,
                              hipStream_t stream) {
  const float* cur = (const float*)d_in[0];   // [8,1024,512] fp32
  const float* hid = (const float*)d_in[1];   // [8,1024,512] fp32
  const float* Wq  = (const float*)d_in[2];   // [512,512]
  const float* Wkv = (const float*)d_in[3];   // [512,1024]
  const float* Wo  = (const float*)d_in[4];   // [512,512]

  ushort_t* ws = (ushort_t*)d_ws;
  // A-region: hid split -> kv-proj; then cur split -> q-proj; then aout hi/lo.
  ushort_t* Ah = ws;                    // 4,194,304
  ushort_t* Al = Ah + 4194304;          // 4,194,304
  ushort_t* kh = Al + 4194304;          // 4,194,304
  ushort_t* kl = kh + 4194304;          // 4,194,304
  ushort_t* vt = kl + 4194304;          // 4,194,304
  ushort_t* qhb = vt + 4194304;         // 4,194,304
  ushort_t* qlb = qhb + 4194304;        // 4,194,304
  ushort_t* WqTh = qlb + 4194304;       // 262,144
  ushort_t* WqTl = WqTh + 262144;       // 262,144
  ushort_t* WkvTh = WqTl + 262144;      // 524,288
  ushort_t* WkvTl = WkvTh + 524288;     // 524,288
  ushort_t* WoTh = WkvTl + 524288;      // 262,144
  ushort_t* WoTl = WoTh + 262144;       // 262,144
  // total ~63 MB

  dim3 tb(32, 8);
  transpose_split<<<dim3(16, 16), tb, 0, stream>>>(Wq, WqTh, WqTl, 512, 512);
  transpose_split<<<dim3(32, 16), tb, 0, stream>>>(Wkv, WkvTh, WkvTl, 512, 1024);
  transpose_split<<<dim3(16, 16), tb, 0, stream>>>(Wo, WoTh, WoTl, 512, 512);

  // kv projection (uses A-region for hid split)
  split8<<<2048, 256, 0, stream>>>(hid, Ah, Al, 4194304 / 8);
  gemm3_bt<1><<<dim3(8, 64), 256, 0, stream>>>(Ah, Al, WkvTh, WkvTl,
                                               kh, kl, vt, (float*)nullptr, 512, 0);
  // q projection (A-region reused for cur split)
  split8<<<2048, 256, 0, stream>>>(cur, Ah, Al, 4194304 / 8);
  gemm3_bt<0><<<dim3(4, 64), 256, 0, stream>>>(Ah, Al, WqTh, WqTl,
                                               qhb, qlb, (ushort_t*)nullptr, (float*)nullptr, 512, 0);
  // attention (A-region reused for aout hi/lo)
  flash_attn<<<512, 256, 0, stream>>>(qhb, qlb, kh, kl, vt, Ah, Al);
  // output projection -> fp32 d_out
  gemm3_bt<2><<<dim3(4, 64), 256, 0, stream>>>(Ah, Al, WoTh, WoTl,
                                               (ushort_t*)nullptr, (ushort_t*)nullptr,
                                               (ushort_t*)nullptr, (float*)d_out, 512, 512);
}

// Round 7
// 255.212 us; speedup vs baseline: 1.0256x; 1.0256x over previous
//
#include <hip/hip_runtime.h>

typedef unsigned short ushort_t;
typedef __attribute__((ext_vector_type(8))) short short8;
typedef __attribute__((ext_vector_type(4))) float f32x4;

#define LOG2E 1.44269504088896f

// async global->LDS, 16B per lane. LDS dest must be wave-uniform base + lane*16.
__device__ __forceinline__ void async16(const void* g, void* l) {
  __builtin_amdgcn_global_load_lds(
      (const __attribute__((address_space(1))) void*)g,
      (__attribute__((address_space(3))) void*)l, 16, 0, 0);
}

__device__ __forceinline__ ushort_t f2bf(float f) {
  union { float f; unsigned u; } x; x.f = f;
  unsigned u = x.u;
  u += 0x7fffu + ((u >> 16) & 1u);
  return (ushort_t)(u >> 16);
}

__device__ __forceinline__ float bf2f(ushort_t w) {
  union { unsigned u; float f; } x; x.u = ((unsigned)w) << 16;
  return x.f;
}

// ---------------- split ingest: fp32 -> (hi, lo) bf16 ----------------
__global__ __launch_bounds__(256) void split8(const float* __restrict__ src,
                                              ushort_t* __restrict__ hi,
                                              ushort_t* __restrict__ lo, int n8) {
  int i = blockIdx.x * 256 + threadIdx.x;
  if (i >= n8) return;
  const f32x4* s = (const f32x4*)src;
  f32x4 a = s[i * 2], b = s[i * 2 + 1];
  short8 oh, ol;
  #pragma unroll
  for (int j = 0; j < 4; j++) {
    ushort_t h = f2bf(a[j]); oh[j] = (short)h; ol[j] = (short)f2bf(a[j] - bf2f(h));
    h = f2bf(b[j]); oh[j + 4] = (short)h; ol[j + 4] = (short)f2bf(b[j] - bf2f(h));
  }
  ((short8*)hi)[i] = oh;
  ((short8*)lo)[i] = ol;
}

// ------- weight transpose+split: src fp32 [K][Nn] -> dstT hi/lo bf16 [Nn][K] -------
__global__ __launch_bounds__(256) void transpose_split(const float* __restrict__ src,
                                                       ushort_t* __restrict__ dh,
                                                       ushort_t* __restrict__ dl,
                                                       int K, int Nn) {
  __shared__ float tile[32][33];
  int bx = blockIdx.x * 32;  // Nn dim
  int by = blockIdx.y * 32;  // K dim
  int tx = threadIdx.x, ty = threadIdx.y;  // (32, 8)
  #pragma unroll
  for (int i = 0; i < 32; i += 8)
    tile[ty + i][tx] = src[(size_t)(by + ty + i) * Nn + bx + tx];
  __syncthreads();
  #pragma unroll
  for (int i = 0; i < 32; i += 8) {
    float v = tile[tx][ty + i];
    ushort_t h = f2bf(v);
    size_t idx = (size_t)(bx + ty + i) * K + by + tx;
    dh[idx] = h;
    dl[idx] = f2bf(v - bf2f(h));
  }
}

// ---- split GEMM: C = (Ah+Al)[M][K] @ (Bh+Bl)[Nn][K]^T, 3-product bf16x3 ----
// BM=128, BN=TN*32. 4 waves (2x2); wave tile = 64 x (TN*16): TN n-tiles, 4 m-tiles.
// EPI 0: C -> (o_hi,o_lo) q-layout [B*H][N][D]
// EPI 1: col<512 -> (o_hi,o_lo) k-layout [B*H][N][D]; col>=512 -> o_vt bf16 [B*H][D][N]
// EPI 2: outf fp32 row-major [M][ldo]  (final output)
template<int EPI, int TN>
__global__ __launch_bounds__(256) void gemm3_bt(const ushort_t* __restrict__ Ah,
                                                const ushort_t* __restrict__ Al,
                                                const ushort_t* __restrict__ Bh,
                                                const ushort_t* __restrict__ Bl,
                                                ushort_t* __restrict__ o_hi,
                                                ushort_t* __restrict__ o_lo,
                                                ushort_t* __restrict__ o_vt,
                                                float* __restrict__ outf,
                                                int K, int ldo) {
  constexpr int BN = TN * 32;
  __shared__ __align__(16) ushort_t Ash[128 * 32];
  __shared__ __align__(16) ushort_t Asl[128 * 32];
  __shared__ __align__(16) ushort_t Bsh[BN * 32];
  __shared__ __align__(16) ushort_t Bsl[BN * 32];
  const int tid = threadIdx.x;
  const int wave = tid >> 6, lane = tid & 63;
  const int wm = (wave >> 1) * 64, wn = (wave & 1) * (TN * 16);
  const int m0 = blockIdx.y * 128, n0 = blockIdx.x * BN;
  const int lrow = lane & 15, lq = lane >> 4;

  f32x4 acc[4][TN];
  const f32x4 z = {0.f, 0.f, 0.f, 0.f};
  #pragma unroll
  for (int i = 0; i < 4; i++)
    #pragma unroll
    for (int j = 0; j < TN; j++) acc[i][j] = z;

  for (int k0 = 0; k0 < K; k0 += 32) {
    __syncthreads();
    #pragma unroll
    for (int i = 0; i < 2; i++) {        // A tile: 128 rows
      int g = i * 256 + tid;             // 0..511
      int r = g >> 2, kc = g & 3;
      size_t ga = (size_t)(m0 + r) * K + k0 + kc * 8;
      async16(&Ah[ga], &Ash[g * 8]);
      async16(&Al[ga], &Asl[g * 8]);
    }
    #pragma unroll
    for (int i = 0; i < BN / 64; i++) {  // B tile: BN rows
      int g = i * 256 + tid;
      int r = g >> 2, kc = g & 3;
      size_t gb = (size_t)(n0 + r) * K + k0 + kc * 8;
      async16(&Bh[gb], &Bsh[g * 8]);
      async16(&Bl[gb], &Bsl[g * 8]);
    }
    __syncthreads();  // drains vmcnt(0): all tiles landed

    short8 afh[4], bfr[TN];
    #pragma unroll
    for (int t = 0; t < 4; t++)
      afh[t] = *(const short8*)&Ash[(wm + t * 16 + lrow) * 32 + lq * 8];
    #pragma unroll
    for (int t = 0; t < TN; t++)
      bfr[t] = *(const short8*)&Bsh[(wn + t * 16 + lrow) * 32 + lq * 8];
    #pragma unroll
    for (int ti = 0; ti < 4; ti++)
      #pragma unroll
      for (int tj = 0; tj < TN; tj++)
        acc[ti][tj] = __builtin_amdgcn_mfma_f32_16x16x32_bf16(afh[ti], bfr[tj], acc[ti][tj], 0, 0, 0);

    {
      short8 afl[4];
      #pragma unroll
      for (int t = 0; t < 4; t++)
        afl[t] = *(const short8*)&Asl[(wm + t * 16 + lrow) * 32 + lq * 8];
      #pragma unroll
      for (int ti = 0; ti < 4; ti++)
        #pragma unroll
        for (int tj = 0; tj < TN; tj++)
          acc[ti][tj] = __builtin_amdgcn_mfma_f32_16x16x32_bf16(afl[ti], bfr[tj], acc[ti][tj], 0, 0, 0);
    }
    #pragma unroll
    for (int t = 0; t < TN; t++)
      bfr[t] = *(const short8*)&Bsl[(wn + t * 16 + lrow) * 32 + lq * 8];
    #pragma unroll
    for (int ti = 0; ti < 4; ti++)
      #pragma unroll
      for (int tj = 0; tj < TN; tj++)
        acc[ti][tj] = __builtin_amdgcn_mfma_f32_16x16x32_bf16(afh[ti], bfr[tj], acc[ti][tj], 0, 0, 0);
  }

  // epilogue: C row m = m0+wm+ti*16+lq*4+r ; col = n0+wn+tj*16+lrow
  #pragma unroll
  for (int ti = 0; ti < 4; ti++) {
    #pragma unroll
    for (int tj = 0; tj < TN; tj++) {
      int row0 = m0 + wm + ti * 16 + lq * 4;
      int col = n0 + wn + tj * 16 + lrow;
      #pragma unroll
      for (int r = 0; r < 4; r++) {
        int m = row0 + r;
        float fv = acc[ti][tj][r];
        if (EPI == 0) {
          size_t idx = (size_t)((m >> 10) * 8 + (col >> 6)) * 65536 + (m & 1023) * 64 + (col & 63);
          ushort_t h = f2bf(fv);
          o_hi[idx] = h;
          o_lo[idx] = f2bf(fv - bf2f(h));
        } else if (EPI == 1) {
          if (col < 512) {
            size_t idx = (size_t)((m >> 10) * 8 + (col >> 6)) * 65536 + (m & 1023) * 64 + (col & 63);
            ushort_t h = f2bf(fv);
            o_hi[idx] = h;
            o_lo[idx] = f2bf(fv - bf2f(h));
          } else {
            int cc = col - 512;
            o_vt[(size_t)(((m >> 10) * 8 + (cc >> 6)) * 64 + (cc & 63)) * 1024 + (m & 1023)] = f2bf(fv);
          }
        } else {
          outf[(size_t)m * ldo + col] = fv;   // fp32 final output
        }
      }
    }
  }
}

// ---------------- flash attention (split-precision QK^T, conflict-free LDS) ------
// grid = B*H*(N/128) = 512 blocks, 256 threads. Wave w owns 32 Q rows.
// K/V staged with padded row stride 72 ushorts (144B = 9 chunks -> uniform banks).
__global__ __launch_bounds__(256) void flash_attn(const ushort_t* __restrict__ qh,
                                                  const ushort_t* __restrict__ ql,
                                                  const ushort_t* __restrict__ kh,
                                                  const ushort_t* __restrict__ kl,
                                                  const ushort_t* __restrict__ vtb,
                                                  ushort_t* __restrict__ obh,
                                                  ushort_t* __restrict__ obl) {
  constexpr int LS = 72;                               // padded row stride (ushorts)
  __shared__ __align__(16) ushort_t Ksh[64 * LS];
  __shared__ __align__(16) ushort_t Ksl[64 * LS];
  __shared__ __align__(16) ushort_t VTs[64 * LS];
  __shared__ __align__(16) float Sw[4][64 * 40];       // per wave: S^T [c][r], stride 40
  __shared__ __align__(16) float albuf[4][32];
  __shared__ __align__(16) float lbuf[4][32];

  const int tid = threadIdx.x;
  const int wave = tid >> 6, lane = tid & 63;
  const int bh = blockIdx.x >> 3, qt = blockIdx.x & 7;
  const int lrow = lane & 15, lq = lane >> 4;
  // P buffer aliases this wave's Sw region (wave-private; S fully consumed
  // via the mx reduction before P overwrites). stride 72 ushorts (bank-uniform).
  ushort_t* Pw = (ushort_t*)&Sw[wave][0];              // [32][72] bf16 = 4608 B

  const ushort_t* Qh = qh + (size_t)bh * 65536;
  const ushort_t* Ql = ql + (size_t)bh * 65536;
  const ushort_t* Kph = kh + (size_t)bh * 65536;
  const ushort_t* Kpl = kl + (size_t)bh * 65536;
  const ushort_t* VT = vtb + (size_t)bh * 65536;

  const int qrow0 = qt * 128 + wave * 32;

  short8 qfh[2][2], qfl[2][2];
  #pragma unroll
  for (int mt = 0; mt < 2; mt++)
    #pragma unroll
    for (int s = 0; s < 2; s++) {
      size_t idx = (size_t)(qrow0 + mt * 16 + lrow) * 64 + s * 32 + lq * 8;
      qfh[mt][s] = *(const short8*)&Qh[idx];
      qfl[mt][s] = *(const short8*)&Ql[idx];
    }

  f32x4 oacc[2][4];
  const f32x4 z = {0.f, 0.f, 0.f, 0.f};
  #pragma unroll
  for (int mt = 0; mt < 2; mt++)
    #pragma unroll
    for (int dt = 0; dt < 4; dt++) oacc[mt][dt] = z;

  float m_i = -1e30f, l_i = 0.f;
  const int r = lane >> 1, hlf = lane & 1;

  for (int kt = 0; kt < 16; kt++) {
    // global loads to VGPR first (overlap previous iteration's compute)
    short8 skh[2], skl[2], sv[2];
    #pragma unroll
    for (int i = 0; i < 2; i++) {
      int g = i * 256 + tid;      // 0..511
      int rw = g >> 3, ch = g & 7;
      size_t kidx = (size_t)(kt * 64 + rw) * 64 + ch * 8;
      skh[i] = *(const short8*)&Kph[kidx];
      skl[i] = *(const short8*)&Kpl[kidx];
      sv[i]  = *(const short8*)&VT[(size_t)rw * 1024 + kt * 64 + ch * 8];
    }
    __syncthreads();  // all waves done with previous K/V tiles
    #pragma unroll
    for (int i = 0; i < 2; i++) {
      int g = i * 256 + tid;
      int rw = g >> 3, ch = g & 7;
      int l = rw * LS + ch * 8;
      *(short8*)&Ksh[l] = skh[i];
      *(short8*)&Ksl[l] = skl[i];
      *(short8*)&VTs[l] = sv[i];
    }
    __syncthreads();  // tiles in LDS

    // S = Q @ K^T with bf16x3: qh*kh + ql*kh + qh*kl
    f32x4 sacc[2][4];
    #pragma unroll
    for (int mt = 0; mt < 2; mt++)
      #pragma unroll
      for (int nt = 0; nt < 4; nt++) sacc[mt][nt] = z;
    #pragma unroll
    for (int s = 0; s < 2; s++) {
      short8 bfr[4];
      #pragma unroll
      for (int nt = 0; nt < 4; nt++)
        bfr[nt] = *(const short8*)&Ksh[(nt * 16 + lrow) * LS + s * 32 + lq * 8];
      #pragma unroll
      for (int mt = 0; mt < 2; mt++)
        #pragma unroll
        for (int nt = 0; nt < 4; nt++) {
          sacc[mt][nt] = __builtin_amdgcn_mfma_f32_16x16x32_bf16(qfh[mt][s], bfr[nt], sacc[mt][nt], 0, 0, 0);
          sacc[mt][nt] = __builtin_amdgcn_mfma_f32_16x16x32_bf16(qfl[mt][s], bfr[nt], sacc[mt][nt], 0, 0, 0);
        }
      #pragma unroll
      for (int nt = 0; nt < 4; nt++)
        bfr[nt] = *(const short8*)&Ksl[(nt * 16 + lrow) * LS + s * 32 + lq * 8];
      #pragma unroll
      for (int mt = 0; mt < 2; mt++)
        #pragma unroll
        for (int nt = 0; nt < 4; nt++)
          sacc[mt][nt] = __builtin_amdgcn_mfma_f32_16x16x32_bf16(qfh[mt][s], bfr[nt], sacc[mt][nt], 0, 0, 0);
    }

    // store S^T to wave-private LDS (C-layout: col=lrow+16nt, rows lq*4+reg+16mt)
    #pragma unroll
    for (int mt = 0; mt < 2; mt++)
      #pragma unroll
      for (int nt = 0; nt < 4; nt++) {
        int c = nt * 16 + lrow;
        int rr = mt * 16 + lq * 4;
        *(f32x4*)&Sw[wave][c * 40 + rr] = sacc[mt][nt];
      }
    __syncthreads();

    // online softmax: lane pair (2r, 2r+1) handles row r, 32 cols each
    float vals[32];
    float mx = -1e30f;
    #pragma unroll
    for (int j = 0; j < 32; j++) {
      vals[j] = Sw[wave][(hlf * 32 + j) * 40 + r];
      mx = fmaxf(mx, vals[j]);
    }
    mx = fmaxf(mx, __shfl_xor(mx, 1));   // consumes ALL vals -> S reads complete
    float mnew = fmaxf(m_i, mx);
    float alpha = exp2f((m_i - mnew) * LOG2E);
    float sum = 0.f;
    #pragma unroll
    for (int j8 = 0; j8 < 4; j8++) {
      short8 pk;
      #pragma unroll
      for (int j = 0; j < 8; j++) {
        float p = exp2f((vals[j8 * 8 + j] - mnew) * LOG2E);
        sum += p;
        pk[j] = (short)f2bf(p);
      }
      *(short8*)&Pw[r * 72 + hlf * 32 + j8 * 8] = pk;   // overwrites Sw alias
    }
    sum += __shfl_xor(sum, 1);
    l_i = l_i * alpha + sum;
    m_i = mnew;
    albuf[wave][r] = alpha;
    __syncthreads();

    // rescale O by alpha (per C-layout row)
    f32x4 al[2];
    #pragma unroll
    for (int mt = 0; mt < 2; mt++) al[mt] = *(f32x4*)&albuf[wave][mt * 16 + lq * 4];
    #pragma unroll
    for (int mt = 0; mt < 2; mt++)
      #pragma unroll
      for (int dt = 0; dt < 4; dt++)
        #pragma unroll
        for (int e = 0; e < 4; e++) oacc[mt][dt][e] *= al[mt][e];

    // O += P @ V
    #pragma unroll
    for (int s = 0; s < 2; s++) {
      short8 pf[2], vf[4];
      #pragma unroll
      for (int mt = 0; mt < 2; mt++)
        pf[mt] = *(const short8*)&Pw[(mt * 16 + lrow) * 72 + s * 32 + lq * 8];
      #pragma unroll
      for (int dt = 0; dt < 4; dt++)
        vf[dt] = *(const short8*)&VTs[(dt * 16 + lrow) * LS + s * 32 + lq * 8];
      #pragma unroll
      for (int mt = 0; mt < 2; mt++)
        #pragma unroll
        for (int dt = 0; dt < 4; dt++)
          oacc[mt][dt] = __builtin_amdgcn_mfma_f32_16x16x32_bf16(pf[mt], vf[dt], oacc[mt][dt], 0, 0, 0);
    }
  }

  // finalize: divide by l, split to hi/lo, write [B][N][H*D]
  lbuf[wave][r] = l_i;
  __syncthreads();
  f32x4 li[2];
  #pragma unroll
  for (int mt = 0; mt < 2; mt++) li[mt] = *(f32x4*)&lbuf[wave][mt * 16 + lq * 4];
  const int b = bh >> 3, h = bh & 7;
  #pragma unroll
  for (int mt = 0; mt < 2; mt++)
    #pragma unroll
    for (int dt = 0; dt < 4; dt++)
      #pragma unroll
      for (int e = 0; e < 4; e++) {
        int n = qt * 128 + wave * 32 + mt * 16 + lq * 4 + e;
        int d = dt * 16 + lrow;
        float f = oacc[mt][dt][e] / li[mt][e];
        size_t idx = (size_t)(b * 1024 + n) * 512 + h * 64 + d;
        ushort_t hi = f2bf(f);
        obh[idx] = hi;
        obl[idx] = f2bf(f - bf2f(hi));
      }
}

// ---------------- launcher ----------------
extern "C" void kernel_launch(void* const* d_in, const int* in_sizes, int n_in,
                              void* d_out, int out_size, void* d_ws, size_t ws_size,
                              hipStream_t stream) {
  const float* cur = (const float*)d_in[0];   // [8,1024,512] fp32
  const float* hid = (const float*)d_in[1];   // [8,1024,512] fp32
  const float* Wq  = (const float*)d_in[2];   // [512,512]
  const float* Wkv = (const float*)d_in[3];   // [512,1024]
  const float* Wo  = (const float*)d_in[4];   // [512,512]

  ushort_t* ws = (ushort_t*)d_ws;
  ushort_t* Ah = ws;                    // 4,194,304  (hid split; reused: cur split; aout hi)
  ushort_t* Al = Ah + 4194304;          // 4,194,304  (… aout lo)
  ushort_t* kh = Al + 4194304;          // 4,194,304
  ushort_t* kl = kh + 4194304;          // 4,194,304
  ushort_t* vt = kl + 4194304;          // 4,194,304
  ushort_t* qhb = vt + 4194304;         // 4,194,304
  ushort_t* qlb = qhb + 4194304;        // 4,194,304
  ushort_t* WqTh = qlb + 4194304;       // 262,144
  ushort_t* WqTl = WqTh + 262144;       // 262,144
  ushort_t* WkvTh = WqTl + 262144;      // 524,288
  ushort_t* WkvTl = WkvTh + 524288;     // 524,288
  ushort_t* WoTh = WkvTl + 524288;      // 262,144
  ushort_t* WoTl = WoTh + 262144;       // 262,144

  dim3 tb(32, 8);
  transpose_split<<<dim3(16, 16), tb, 0, stream>>>(Wq, WqTh, WqTl, 512, 512);
  transpose_split<<<dim3(32, 16), tb, 0, stream>>>(Wkv, WkvTh, WkvTl, 512, 1024);
  transpose_split<<<dim3(16, 16), tb, 0, stream>>>(Wo, WoTh, WoTl, 512, 512);

  // kv projection (BN=128): 512 blocks
  split8<<<2048, 256, 0, stream>>>(hid, Ah, Al, 4194304 / 8);
  gemm3_bt<1, 4><<<dim3(8, 64), 256, 0, stream>>>(Ah, Al, WkvTh, WkvTl,
                                                  kh, kl, vt, (float*)nullptr, 512, 0);
  // q projection (BN=64): 512 blocks
  split8<<<2048, 256, 0, stream>>>(cur, Ah, Al, 4194304 / 8);
  gemm3_bt<0, 2><<<dim3(8, 64), 256, 0, stream>>>(Ah, Al, WqTh, WqTl,
                                                  qhb, qlb, (ushort_t*)nullptr, (float*)nullptr, 512, 0);
  // attention (A-region reused for aout hi/lo)
  flash_attn<<<512, 256, 0, stream>>>(qhb, qlb, kh, kl, vt, Ah, Al);
  // output projection (BN=64) -> fp32 d_out: 512 blocks
  gemm3_bt<2, 2><<<dim3(8, 64), 256, 0, stream>>>(Ah, Al, WoTh, WoTl,
                                                  (ushort_t*)nullptr, (ushort_t*)nullptr,
                                                  (ushort_t*)nullptr, (float*)d_out, 512, 512);
}